// Round 5
// baseline (2100.291 us; speedup 1.0000x reference)
//
#include <hip/hip_runtime.h>
#include <hip/hip_bf16.h>

// NewellGRUModel: B=512, S=1024, F=16, H=64.  bf16 in/out (round 2 proof:
// FETCH_SIZE == bf16 input bytes, absmax 0.0, LDS size matched bf16 path).
//
// Round 2 structure (the only source proven to execute) with two changes:
//  1. Hot-loop __syncthreads() -> asm compiler fence. Blocks are one wave;
//     DS ops within a wave execute in program order, so no s_barrier (and
//     no vmcnt/lgkmcnt full drain) is needed -- only compiler ordering.
//  2. Two batch items per wave (grid 256: b and b+256). The two recurrences
//     are independent serial chains; interleaving them hides LDS latency and
//     FMA dependency chains under issue. Weights are shared (register cost
//     unchanged); per-batch state doubles.
// All constructs (IO template, float4 LDS reads, fmaf, __expf, rcp, shuffle
// reduce, detect scaffold) are exactly round 2's -- nothing new.

template<bool BF16>
struct IO {
    static __device__ __forceinline__ float ld(const void* p, int i) {
        if constexpr (BF16) {
            unsigned short u = ((const unsigned short*)p)[i];
            union { unsigned int ui; float f; } c; c.ui = (unsigned int)u << 16;
            return c.f;
        } else {
            return ((const float*)p)[i];
        }
    }
    static __device__ __forceinline__ float4 ld4(const void* p, int i) {
        if constexpr (BF16) {
            uint2 raw = *(const uint2*)((const unsigned short*)p + i);
            union { unsigned int ui; float f; } c0, c1, c2, c3;
            c0.ui = raw.x << 16; c1.ui = raw.x & 0xffff0000u;
            c2.ui = raw.y << 16; c3.ui = raw.y & 0xffff0000u;
            return make_float4(c0.f, c1.f, c2.f, c3.f);
        } else {
            return *(const float4*)((const float*)p + i);
        }
    }
    static __device__ __forceinline__ void st(void* p, int i, float v) {
        if constexpr (BF16) ((__hip_bfloat16*)p)[i] = __float2bfloat16(v);
        else ((float*)p)[i] = v;
    }
};

// mode: 0 = buffers are bf16, 1 = buffers are fp32.
__global__ void detect_dtype_kernel(const void* rkbuf, int* flag) {
    const float* f = (const float*)rkbuf;
    int ok = 0;
    for (int i = 0; i < 64; ++i) {
        float a = fabsf(f[i]);
        ok += (a > 1e-5f && a < 2.0f) ? 1 : 0;
    }
    *flag = (ok >= 48) ? 1 : 0;
}

template<bool BF16>
__global__ __launch_bounds__(64, 1)
void gru_full_kernel(const void* __restrict__ inp, const void* __restrict__ gk,
                     const void* __restrict__ rk,  const void* __restrict__ gb,
                     const void* __restrict__ w1,  const void* __restrict__ b1v,
                     const void* __restrict__ gam, const void* __restrict__ bet,
                     const void* __restrict__ muv, const void* __restrict__ vav,
                     const void* __restrict__ w2,  const void* __restrict__ bb2,
                     const void* __restrict__ Tp,  const int* __restrict__ mode,
                     void* __restrict__ out)
{
    const int want = BF16 ? 0 : 1;
    if (*mode != want) return;   // uniform branch, whole block exits

    const int b0 = blockIdx.x;         // batch A
    const int b1 = blockIdx.x + 256;   // batch B
    const int j  = threadIdx.x;        // 0..63

    __shared__ __align__(16) float xsA[2][16][16];  // [buf][step][channel]
    __shared__ __align__(16) float xsB[2][16][16];
    __shared__ __align__(16) float hsA[2][64];      // double-buffered h
    __shared__ __align__(16) float hsB[2][64];

    using io = IO<BF16>;

    // ---- weights into registers (shared by both batches) ----
    float wz[64], wr[64], wh[64];
#pragma unroll
    for (int k = 0; k < 64; ++k) {
        wz[k] = io::ld(rk, k*192 + j);
        wr[k] = io::ld(rk, k*192 + 64 + j);
        wh[k] = io::ld(rk, k*192 + 128 + j);
    }
    float kz[15], kr[15], kh[15];
#pragma unroll
    for (int k = 0; k < 15; ++k) {
        kz[k] = io::ld(gk, k*192 + j);
        kr[k] = io::ld(gk, k*192 + 64 + j);
        kh[k] = io::ld(gk, k*192 + 128 + j);
    }
    // gru_bias[0]=b_i (input proj), gru_bias[1]=b_r (recurrent)
    const float bz  = io::ld(gb, j)        + io::ld(gb, 192 + j);
    const float br  = io::ld(gb, 64 + j)   + io::ld(gb, 192 + 64 + j);
    const float bih = io::ld(gb, 128 + j);
    const float brh = io::ld(gb, 192 + 128 + j);

    hsA[0][j] = 0.0f;    // h0 = 0
    hsB[0][j] = 0.0f;

    const int xb0 = b0 * 16384;   // elements
    const int xb1 = b1 * 16384;
    float4 nxA = io::ld4(inp, xb0 + j * 4);   // prefetch tile 0
    float4 nxB = io::ld4(inp, xb1 + j * 4);

    float ha = 0.0f, hb = 0.0f, dsA = 0.0f, dsB = 0.0f;

#pragma unroll 1
    for (int t = 0; t < 64; ++t) {
        ((float4*)&xsA[t & 1][0][0])[j] = nxA;
        ((float4*)&xsB[t & 1][0][0])[j] = nxB;
        if (t < 63) {
            nxA = io::ld4(inp, xb0 + (t + 1) * 256 + j * 4);
            nxB = io::ld4(inp, xb1 + (t + 1) * 256 + j * 4);
        }
        asm volatile("" ::: "memory");   // wave-synchronous LDS: no s_barrier

#pragma unroll 1
        for (int s2 = 0; s2 < 16; ++s2) {
            const int s = t * 16 + s2;

            const float4* xrA = (const float4*)&xsA[t & 1][s2][0];
            const float4* xrB = (const float4*)&xsB[t & 1][s2][0];
            float xfA[16], xfB[16];
            {
                float4 q;
                q = xrA[0]; xfA[0]=q.x;  xfA[1]=q.y;  xfA[2]=q.z;  xfA[3]=q.w;
                q = xrA[1]; xfA[4]=q.x;  xfA[5]=q.y;  xfA[6]=q.z;  xfA[7]=q.w;
                q = xrA[2]; xfA[8]=q.x;  xfA[9]=q.y;  xfA[10]=q.z; xfA[11]=q.w;
                q = xrA[3]; xfA[12]=q.x; xfA[13]=q.y; xfA[14]=q.z; xfA[15]=q.w;
                q = xrB[0]; xfB[0]=q.x;  xfB[1]=q.y;  xfB[2]=q.z;  xfB[3]=q.w;
                q = xrB[1]; xfB[4]=q.x;  xfB[5]=q.y;  xfB[6]=q.z;  xfB[7]=q.w;
                q = xrB[2]; xfB[8]=q.x;  xfB[9]=q.y;  xfB[10]=q.z; xfB[11]=q.w;
                q = xrB[3]; xfB[12]=q.x; xfB[13]=q.y; xfB[14]=q.z; xfB[15]=q.w;
            }

            float azA = bz, arA = br, axA = bih, ahA = brh;
            float azB = bz, arB = br, axB = bih, ahB = brh;
#pragma unroll
            for (int k = 0; k < 15; ++k) {
                azA = fmaf(xfA[k], kz[k], azA);  azB = fmaf(xfB[k], kz[k], azB);
                arA = fmaf(xfA[k], kr[k], arA);  arB = fmaf(xfB[k], kr[k], arB);
                axA = fmaf(xfA[k], kh[k], axA);  axB = fmaf(xfB[k], kh[k], axB);
            }
            dsA += xfA[15];   // channel 15 = delta_x_shifted
            dsB += xfB[15];

            const float4* hpA = (const float4*)&hsA[s & 1][0];
            const float4* hpB = (const float4*)&hsB[s & 1][0];
#pragma unroll
            for (int i = 0; i < 16; ++i) {
                float4 pA = hpA[i], pB = hpB[i];
                azA = fmaf(pA.x, wz[4*i+0], azA);  azB = fmaf(pB.x, wz[4*i+0], azB);
                arA = fmaf(pA.x, wr[4*i+0], arA);  arB = fmaf(pB.x, wr[4*i+0], arB);
                ahA = fmaf(pA.x, wh[4*i+0], ahA);  ahB = fmaf(pB.x, wh[4*i+0], ahB);
                azA = fmaf(pA.y, wz[4*i+1], azA);  azB = fmaf(pB.y, wz[4*i+1], azB);
                arA = fmaf(pA.y, wr[4*i+1], arA);  arB = fmaf(pB.y, wr[4*i+1], arB);
                ahA = fmaf(pA.y, wh[4*i+1], ahA);  ahB = fmaf(pB.y, wh[4*i+1], ahB);
                azA = fmaf(pA.z, wz[4*i+2], azA);  azB = fmaf(pB.z, wz[4*i+2], azB);
                arA = fmaf(pA.z, wr[4*i+2], arA);  arB = fmaf(pB.z, wr[4*i+2], arB);
                ahA = fmaf(pA.z, wh[4*i+2], ahA);  ahB = fmaf(pB.z, wh[4*i+2], ahB);
                azA = fmaf(pA.w, wz[4*i+3], azA);  azB = fmaf(pB.w, wz[4*i+3], azB);
                arA = fmaf(pA.w, wr[4*i+3], arA);  arB = fmaf(pB.w, wr[4*i+3], arB);
                ahA = fmaf(pA.w, wh[4*i+3], ahA);  ahB = fmaf(pB.w, wh[4*i+3], ahB);
            }

            const float zA   = __builtin_amdgcn_rcpf(1.0f + __expf(-azA));
            const float rA   = __builtin_amdgcn_rcpf(1.0f + __expf(-arA));
            const float preA = fmaf(rA, ahA, axA);
            const float e2A  = __expf(2.0f * preA);
            const float thA  = 1.0f - 2.0f * __builtin_amdgcn_rcpf(e2A + 1.0f);
            ha = fmaf(zA, ha - thA, thA);   // z*h + (1-z)*tanh

            const float zB   = __builtin_amdgcn_rcpf(1.0f + __expf(-azB));
            const float rB   = __builtin_amdgcn_rcpf(1.0f + __expf(-arB));
            const float preB = fmaf(rB, ahB, axB);
            const float e2B  = __expf(2.0f * preB);
            const float thB  = 1.0f - 2.0f * __builtin_amdgcn_rcpf(e2B + 1.0f);
            hb = fmaf(zB, hb - thB, thB);

            hsA[(s + 1) & 1][j] = ha;
            hsB[(s + 1) & 1][j] = hb;
            asm volatile("" ::: "memory");   // order DS write -> next read
        }
    }

    // ---- epilogue: delta effect + dense head (cold path, keep barriers) ----
    const float T0 = io::ld(Tp, 0);
    hsA[0][j] = fmaf(T0 * (1.0f / 1024.0f), dsA, ha);
    hsB[0][j] = fmaf(T0 * (1.0f / 1024.0f), dsB, hb);
    __syncthreads();

    float accA = io::ld(b1v, j);
    float accB = accA;
#pragma unroll
    for (int k = 0; k < 64; ++k) {
        const float w = io::ld(w1, k*64 + j);
        accA = fmaf(hsA[0][k], w, accA);
        accB = fmaf(hsB[0][k], w, accB);
    }
    const float mu  = io::ld(muv, j);
    const float inv = rsqrtf(io::ld(vav, j) + 0.001f);   // BN_EPS
    const float ga  = io::ld(gam, j);
    const float be  = io::ld(bet, j);
    accA = fmaf((fmaxf(accA, 0.0f) - mu) * inv, ga, be); // ReLU + BN
    accB = fmaf((fmaxf(accB, 0.0f) - mu) * inv, ga, be);

    const float w2j = io::ld(w2, j);
    float vA = accA * w2j;
    float vB = accB * w2j;
#pragma unroll
    for (int off = 32; off > 0; off >>= 1) {
        vA += __shfl_down(vA, off);
        vB += __shfl_down(vB, off);
    }
    if (j == 0) {
        const float c2 = io::ld(bb2, 0);
        io::st(out, b0, vA + c2);
        io::st(out, b1, vB + c2);
    }
}

extern "C" void kernel_launch(void* const* d_in, const int* in_sizes, int n_in,
                              void* d_out, int out_size, void* d_ws, size_t ws_size,
                              hipStream_t stream)
{
    const void* inp = d_in[0];   // (512,1024,16)
    const void* gk  = d_in[1];   // (15,192)
    const void* rk  = d_in[2];   // (64,192)
    const void* gb  = d_in[3];   // (2,192)
    const void* w1  = d_in[4];   // (64,64)
    const void* b1v = d_in[5];   // (64,)
    const void* gam = d_in[6];
    const void* bet = d_in[7];
    const void* muv = d_in[8];
    const void* vav = d_in[9];
    const void* w2  = d_in[10];  // (64,1)
    const void* bb2 = d_in[11];  // (1,)
    const void* Tp  = d_in[12];  // (1,)

    int* flag = (int*)d_ws;
    detect_dtype_kernel<<<dim3(1), dim3(1), 0, stream>>>(rk, flag);
    gru_full_kernel<true ><<<dim3(256), dim3(64), 0, stream>>>(
        inp, gk, rk, gb, w1, b1v, gam, bet, muv, vav, w2, bb2, Tp, flag, d_out);
    gru_full_kernel<false><<<dim3(256), dim3(64), 0, stream>>>(
        inp, gk, rk, gb, w1, b1v, gam, bet, muv, vav, w2, bb2, Tp, flag, d_out);
}

// Round 6
// 1110.315 us; speedup vs baseline: 1.8916x; 1.8916x over previous
//
#include <hip/hip_runtime.h>
#include <hip/hip_bf16.h>

// NewellGRUModel: B=512, S=1024, F=16, H=64.  bf16 in/out (proven r2/r5).
//
// Mapping (proven fastest, round 2): 512 single-wave blocks, lane j owns
// hidden unit j and gate columns (j, 64+j, 128+j).
// Changes vs round 2:
//  - NO s_barrier in hot loop (proven safe in round 5: single-wave block,
//    DS pipe is in-order per wave; asm fence pins compiler order).
//  - x read straight from global: all 64 lanes load the SAME 32B per step
//    (one cache line, broadcast), prefetched 1 step ahead into registers.
//    No x LDS tile, no staging stores, no tile loop.
//  - Single h LDS buffer (reads precede the write in program order).
//  - Accumulators split 2-way per gate to halve serial FMA chains.
//  - h float4 reads consumed immediately (no hf[64] array) to cap VGPRs.
// Constructs strictly from the proven-to-build set: unions/shifts, fmaf,
// __expf, rcpf, __shfl_down, asm fence, detect scaffold.

template<bool BF16>
struct IO {
    static __device__ __forceinline__ float ld(const void* p, int i) {
        if constexpr (BF16) {
            unsigned short u = ((const unsigned short*)p)[i];
            union { unsigned int ui; float f; } c; c.ui = (unsigned int)u << 16;
            return c.f;
        } else {
            return ((const float*)p)[i];
        }
    }
    static __device__ __forceinline__ void st(void* p, int i, float v) {
        if constexpr (BF16) ((__hip_bfloat16*)p)[i] = __float2bfloat16(v);
        else ((float*)p)[i] = v;
    }
};

// Raw per-step x row (16 values), native width per dtype.
template<bool BF16> struct XR;
template<> struct XR<true>  { uint4 a; uint4 b; };
template<> struct XR<false> { float4 a; float4 b; float4 c; float4 d; };

template<bool BF16>
__device__ __forceinline__ XR<BF16> ldx(const void* p, int i) {
    XR<BF16> r;
    if constexpr (BF16) {
        const uint4* q = (const uint4*)((const unsigned short*)p + i);
        r.a = q[0]; r.b = q[1];
    } else {
        const float4* q = (const float4*)((const float*)p + i);
        r.a = q[0]; r.b = q[1]; r.c = q[2]; r.d = q[3];
    }
    return r;
}

template<bool BF16>
__device__ __forceinline__ void unx(const XR<BF16>& r, float* xf) {
    if constexpr (BF16) {
        union { unsigned int ui; float f; } c;
        const unsigned int u[8] = {r.a.x, r.a.y, r.a.z, r.a.w,
                                   r.b.x, r.b.y, r.b.z, r.b.w};
#pragma unroll
        for (int i = 0; i < 8; ++i) {
            c.ui = u[i] << 16;         xf[2*i]   = c.f;
            c.ui = u[i] & 0xffff0000u; xf[2*i+1] = c.f;
        }
    } else {
        xf[0]=r.a.x; xf[1]=r.a.y; xf[2]=r.a.z; xf[3]=r.a.w;
        xf[4]=r.b.x; xf[5]=r.b.y; xf[6]=r.b.z; xf[7]=r.b.w;
        xf[8]=r.c.x; xf[9]=r.c.y; xf[10]=r.c.z; xf[11]=r.c.w;
        xf[12]=r.d.x; xf[13]=r.d.y; xf[14]=r.d.z; xf[15]=r.d.w;
    }
}

// mode: 0 = buffers are bf16, 1 = buffers are fp32.
__global__ void detect_dtype_kernel(const void* rkbuf, int* flag) {
    const float* f = (const float*)rkbuf;
    int ok = 0;
    for (int i = 0; i < 64; ++i) {
        float a = fabsf(f[i]);
        ok += (a > 1e-5f && a < 2.0f) ? 1 : 0;
    }
    *flag = (ok >= 48) ? 1 : 0;
}

template<bool BF16>
__global__ __launch_bounds__(64, 1)
void gru_full_kernel(const void* __restrict__ inp, const void* __restrict__ gk,
                     const void* __restrict__ rk,  const void* __restrict__ gb,
                     const void* __restrict__ w1,  const void* __restrict__ b1v,
                     const void* __restrict__ gam, const void* __restrict__ bet,
                     const void* __restrict__ muv, const void* __restrict__ vav,
                     const void* __restrict__ w2,  const void* __restrict__ bb2,
                     const void* __restrict__ Tp,  const int* __restrict__ mode,
                     void* __restrict__ out)
{
    const int want = BF16 ? 0 : 1;
    if (*mode != want) return;   // uniform branch, whole block exits

    const int b = blockIdx.x;
    const int j = threadIdx.x;   // 0..63

    __shared__ __align__(16) float hs[64];    // single-buffer hidden state
    __shared__ __align__(16) float sred[64];  // epilogue exchange

    using io = IO<BF16>;

    // ---- weights into registers ----
    float wz[64], wr[64], wh[64];
#pragma unroll
    for (int k = 0; k < 64; ++k) {
        wz[k] = io::ld(rk, k*192 + j);
        wr[k] = io::ld(rk, k*192 + 64 + j);
        wh[k] = io::ld(rk, k*192 + 128 + j);
    }
    float kz[15], kr[15], kh[15];
#pragma unroll
    for (int k = 0; k < 15; ++k) {
        kz[k] = io::ld(gk, k*192 + j);
        kr[k] = io::ld(gk, k*192 + 64 + j);
        kh[k] = io::ld(gk, k*192 + 128 + j);
    }
    // gru_bias[0]=b_i (input proj), gru_bias[1]=b_r (recurrent)
    const float bz  = io::ld(gb, j)        + io::ld(gb, 192 + j);
    const float br  = io::ld(gb, 64 + j)   + io::ld(gb, 192 + 64 + j);
    const float bih = io::ld(gb, 128 + j);
    const float brh = io::ld(gb, 192 + 128 + j);

    hs[j] = 0.0f;                  // h0 = 0
    asm volatile("" ::: "memory");

    const int xbase = b * 16384;   // elements
    XR<BF16> craw = ldx<BF16>(inp, xbase);   // step 0 row (all lanes same addr)

    float h = 0.0f, dsum = 0.0f;

#pragma unroll 1
    for (int s = 0; s < 1024; ++s) {
        // prefetch next step's x row (branchless clamp keeps it in-bounds)
        const int snx = (s < 1023) ? (s + 1) : s;
        XR<BF16> nraw = ldx<BF16>(inp, xbase + snx * 16);

        // unpack current x row (wave-uniform values)
        float xf[16];
        unx<BF16>(craw, xf);

        // split accumulators: two independent chains per gate
        float az0 = bz,  ar0 = br,  ah0 = brh;
        float az1 = 0.f, ar1 = 0.f, ah1 = 0.f;
        float ax0 = bih, ax1 = 0.f;
#pragma unroll
        for (int k = 0; k < 8; ++k) {
            az0 = fmaf(xf[k], kz[k], az0);
            ar0 = fmaf(xf[k], kr[k], ar0);
            ax0 = fmaf(xf[k], kh[k], ax0);
        }
#pragma unroll
        for (int k = 8; k < 15; ++k) {
            az1 = fmaf(xf[k], kz[k], az1);
            ar1 = fmaf(xf[k], kr[k], ar1);
            ax1 = fmaf(xf[k], kh[k], ax1);
        }
        dsum += xf[15];            // channel 15 = delta_x_shifted

        // h-part: 16 broadcast ds_read_b128, consumed immediately
        const float4* hp = (const float4*)hs;
#pragma unroll
        for (int i = 0; i < 8; ++i) {
            float4 p = hp[i];
            az0 = fmaf(p.x, wz[4*i+0], az0);
            ar0 = fmaf(p.x, wr[4*i+0], ar0);
            ah0 = fmaf(p.x, wh[4*i+0], ah0);
            az0 = fmaf(p.y, wz[4*i+1], az0);
            ar0 = fmaf(p.y, wr[4*i+1], ar0);
            ah0 = fmaf(p.y, wh[4*i+1], ah0);
            az0 = fmaf(p.z, wz[4*i+2], az0);
            ar0 = fmaf(p.z, wr[4*i+2], ar0);
            ah0 = fmaf(p.z, wh[4*i+2], ah0);
            az0 = fmaf(p.w, wz[4*i+3], az0);
            ar0 = fmaf(p.w, wr[4*i+3], ar0);
            ah0 = fmaf(p.w, wh[4*i+3], ah0);
        }
#pragma unroll
        for (int i = 8; i < 16; ++i) {
            float4 p = hp[i];
            az1 = fmaf(p.x, wz[4*i+0], az1);
            ar1 = fmaf(p.x, wr[4*i+0], ar1);
            ah1 = fmaf(p.x, wh[4*i+0], ah1);
            az1 = fmaf(p.y, wz[4*i+1], az1);
            ar1 = fmaf(p.y, wr[4*i+1], ar1);
            ah1 = fmaf(p.y, wh[4*i+1], ah1);
            az1 = fmaf(p.z, wz[4*i+2], az1);
            ar1 = fmaf(p.z, wr[4*i+2], ar1);
            ah1 = fmaf(p.z, wh[4*i+2], ah1);
            az1 = fmaf(p.w, wz[4*i+3], az1);
            ar1 = fmaf(p.w, wr[4*i+3], ar1);
            ah1 = fmaf(p.w, wh[4*i+3], ah1);
        }

        const float az = az0 + az1;
        const float ar = ar0 + ar1;
        const float ax = ax0 + ax1;
        const float ah = ah0 + ah1;

        const float z   = __builtin_amdgcn_rcpf(1.0f + __expf(-az));
        const float r   = __builtin_amdgcn_rcpf(1.0f + __expf(-ar));
        const float pre = fmaf(r, ah, ax);
        const float e2  = __expf(2.0f * pre);
        const float th  = 1.0f - 2.0f * __builtin_amdgcn_rcpf(e2 + 1.0f);
        h = fmaf(z, h - th, th);   // z*h + (1-z)*tanh

        hs[j] = h;                 // single buffer: all reads above precede
        asm volatile("" ::: "memory");   // pin DS order (no s_barrier)

        craw = nraw;
    }

    // ---- epilogue: delta effect + dense head, all in-wave ----
    const float T0 = io::ld(Tp, 0);
    sred[j] = fmaf(T0 * (1.0f / 1024.0f), dsum, h);
    asm volatile("" ::: "memory");

    float acc = io::ld(b1v, j);
#pragma unroll
    for (int k = 0; k < 64; ++k)
        acc = fmaf(sred[k], io::ld(w1, k*64 + j), acc);
    acc = fmaxf(acc, 0.0f);                                  // ReLU
    const float inv = rsqrtf(io::ld(vav, j) + 0.001f);       // BN_EPS
    acc = fmaf((acc - io::ld(muv, j)) * inv, io::ld(gam, j), io::ld(bet, j));

    float v = acc * io::ld(w2, j);
#pragma unroll
    for (int off = 32; off > 0; off >>= 1)
        v += __shfl_down(v, off);
    if (j == 0) io::st(out, b, v + io::ld(bb2, 0));
}

extern "C" void kernel_launch(void* const* d_in, const int* in_sizes, int n_in,
                              void* d_out, int out_size, void* d_ws, size_t ws_size,
                              hipStream_t stream)
{
    const void* inp = d_in[0];   // (512,1024,16)
    const void* gk  = d_in[1];   // (15,192)
    const void* rk  = d_in[2];   // (64,192)
    const void* gb  = d_in[3];   // (2,192)
    const void* w1  = d_in[4];   // (64,64)
    const void* b1v = d_in[5];   // (64,)
    const void* gam = d_in[6];
    const void* bet = d_in[7];
    const void* muv = d_in[8];
    const void* vav = d_in[9];
    const void* w2  = d_in[10];  // (64,1)
    const void* bb2 = d_in[11];  // (1,)
    const void* Tp  = d_in[12];  // (1,)

    int* flag = (int*)d_ws;
    detect_dtype_kernel<<<dim3(1), dim3(1), 0, stream>>>(rk, flag);
    gru_full_kernel<true ><<<dim3(512), dim3(64), 0, stream>>>(
        inp, gk, rk, gb, w1, b1v, gam, bet, muv, vav, w2, bb2, Tp, flag, d_out);
    gru_full_kernel<false><<<dim3(512), dim3(64), 0, stream>>>(
        inp, gk, rk, gb, w1, b1v, gam, bet, muv, vav, w2, bb2, Tp, flag, d_out);
}

// Round 7
// 1038.402 us; speedup vs baseline: 2.0226x; 1.0693x over previous
//
#include <hip/hip_runtime.h>
#include <hip/hip_bf16.h>

// NewellGRUModel: B=512, S=1024, F=16, H=64.  bf16 in/out (proven r2/r5/r6).
//
// Structure = round 6 (proven, absmax 0.0) with ONE change:
//   All 16 ds_read_b128 of the h vector are force-hoisted to the TOP of the
//   step body into named float4s, separated from consumption by an asm
//   memory fence (hard scheduling barrier: loads cannot sink past it).
//   Round 2/6's 2722 cyc/step matched 16x(120cyc LDS latency + consume)
//   serialization -- the compiler was interleaving each read with its FMAs.
//   Hoisting pipelines the 16 reads; their latency hides under the x-part
//   (unpack + 45 FMAs) which needs no LDS data.
// Everything else unchanged: 512 single-wave blocks, lane j owns unit j and
// gate columns (j,64+j,128+j), no s_barrier in hot loop (single-wave block,
// in-order DS pipe), x read direct from global (same-address broadcast)
// prefetched one step ahead, single h LDS buffer, detect scaffold.

template<bool BF16>
struct IO {
    static __device__ __forceinline__ float ld(const void* p, int i) {
        if constexpr (BF16) {
            unsigned short u = ((const unsigned short*)p)[i];
            union { unsigned int ui; float f; } c; c.ui = (unsigned int)u << 16;
            return c.f;
        } else {
            return ((const float*)p)[i];
        }
    }
    static __device__ __forceinline__ void st(void* p, int i, float v) {
        if constexpr (BF16) ((__hip_bfloat16*)p)[i] = __float2bfloat16(v);
        else ((float*)p)[i] = v;
    }
};

// Raw per-step x row (16 values), native width per dtype.
template<bool BF16> struct XR;
template<> struct XR<true>  { uint4 a; uint4 b; };
template<> struct XR<false> { float4 a; float4 b; float4 c; float4 d; };

template<bool BF16>
__device__ __forceinline__ XR<BF16> ldx(const void* p, int i) {
    XR<BF16> r;
    if constexpr (BF16) {
        const uint4* q = (const uint4*)((const unsigned short*)p + i);
        r.a = q[0]; r.b = q[1];
    } else {
        const float4* q = (const float4*)((const float*)p + i);
        r.a = q[0]; r.b = q[1]; r.c = q[2]; r.d = q[3];
    }
    return r;
}

template<bool BF16>
__device__ __forceinline__ void unx(const XR<BF16>& r, float* xf) {
    if constexpr (BF16) {
        union { unsigned int ui; float f; } c;
        const unsigned int u[8] = {r.a.x, r.a.y, r.a.z, r.a.w,
                                   r.b.x, r.b.y, r.b.z, r.b.w};
#pragma unroll
        for (int i = 0; i < 8; ++i) {
            c.ui = u[i] << 16;         xf[2*i]   = c.f;
            c.ui = u[i] & 0xffff0000u; xf[2*i+1] = c.f;
        }
    } else {
        xf[0]=r.a.x; xf[1]=r.a.y; xf[2]=r.a.z; xf[3]=r.a.w;
        xf[4]=r.b.x; xf[5]=r.b.y; xf[6]=r.b.z; xf[7]=r.b.w;
        xf[8]=r.c.x; xf[9]=r.c.y; xf[10]=r.c.z; xf[11]=r.c.w;
        xf[12]=r.d.x; xf[13]=r.d.y; xf[14]=r.d.z; xf[15]=r.d.w;
    }
}

// mode: 0 = buffers are bf16, 1 = buffers are fp32.
__global__ void detect_dtype_kernel(const void* rkbuf, int* flag) {
    const float* f = (const float*)rkbuf;
    int ok = 0;
    for (int i = 0; i < 64; ++i) {
        float a = fabsf(f[i]);
        ok += (a > 1e-5f && a < 2.0f) ? 1 : 0;
    }
    *flag = (ok >= 48) ? 1 : 0;
}

template<bool BF16>
__global__ __launch_bounds__(64, 1)
void gru_full_kernel(const void* __restrict__ inp, const void* __restrict__ gk,
                     const void* __restrict__ rk,  const void* __restrict__ gb,
                     const void* __restrict__ w1,  const void* __restrict__ b1v,
                     const void* __restrict__ gam, const void* __restrict__ bet,
                     const void* __restrict__ muv, const void* __restrict__ vav,
                     const void* __restrict__ w2,  const void* __restrict__ bb2,
                     const void* __restrict__ Tp,  const int* __restrict__ mode,
                     void* __restrict__ out)
{
    const int want = BF16 ? 0 : 1;
    if (*mode != want) return;   // uniform branch, whole block exits

    const int b = blockIdx.x;
    const int j = threadIdx.x;   // 0..63

    __shared__ __align__(16) float hs[64];    // single-buffer hidden state
    __shared__ __align__(16) float sred[64];  // epilogue exchange

    using io = IO<BF16>;

    // ---- weights into registers ----
    float wz[64], wr[64], wh[64];
#pragma unroll
    for (int k = 0; k < 64; ++k) {
        wz[k] = io::ld(rk, k*192 + j);
        wr[k] = io::ld(rk, k*192 + 64 + j);
        wh[k] = io::ld(rk, k*192 + 128 + j);
    }
    float kz[15], kr[15], kh[15];
#pragma unroll
    for (int k = 0; k < 15; ++k) {
        kz[k] = io::ld(gk, k*192 + j);
        kr[k] = io::ld(gk, k*192 + 64 + j);
        kh[k] = io::ld(gk, k*192 + 128 + j);
    }
    // gru_bias[0]=b_i (input proj), gru_bias[1]=b_r (recurrent)
    const float bz  = io::ld(gb, j)        + io::ld(gb, 192 + j);
    const float br  = io::ld(gb, 64 + j)   + io::ld(gb, 192 + 64 + j);
    const float bih = io::ld(gb, 128 + j);
    const float brh = io::ld(gb, 192 + 128 + j);

    hs[j] = 0.0f;                  // h0 = 0
    asm volatile("" ::: "memory");

    const int xbase = b * 16384;   // elements
    XR<BF16> craw = ldx<BF16>(inp, xbase);   // step 0 row (all lanes same addr)

    float h = 0.0f, dsum = 0.0f;

#pragma unroll 1
    for (int s = 0; s < 1024; ++s) {
        // prefetch next step's x row (branchless clamp keeps it in-bounds)
        const int snx = (s < 1023) ? (s + 1) : s;
        XR<BF16> nraw = ldx<BF16>(inp, xbase + snx * 16);

        // ---- issue ALL 16 h reads up front (pipelined in the DS unit) ----
        const float4* hp = (const float4*)hs;
        float4 p0  = hp[0],  p1  = hp[1],  p2  = hp[2],  p3  = hp[3];
        float4 p4  = hp[4],  p5  = hp[5],  p6  = hp[6],  p7  = hp[7];
        float4 p8  = hp[8],  p9  = hp[9],  p10 = hp[10], p11 = hp[11];
        float4 p12 = hp[12], p13 = hp[13], p14 = hp[14], p15 = hp[15];
        asm volatile("" ::: "memory");   // loads may not sink past this

        // unpack current x row (wave-uniform values) -- no LDS dependence,
        // hides the ds_read latency
        float xf[16];
        unx<BF16>(craw, xf);

        // split accumulators: two independent chains per gate
        float az0 = bz,  ar0 = br,  ah0 = brh;
        float az1 = 0.f, ar1 = 0.f, ah1 = 0.f;
        float ax0 = bih, ax1 = 0.f;
#pragma unroll
        for (int k = 0; k < 8; ++k) {
            az0 = fmaf(xf[k], kz[k], az0);
            ar0 = fmaf(xf[k], kr[k], ar0);
            ax0 = fmaf(xf[k], kh[k], ax0);
        }
#pragma unroll
        for (int k = 8; k < 15; ++k) {
            az1 = fmaf(xf[k], kz[k], az1);
            ar1 = fmaf(xf[k], kr[k], ar1);
            ax1 = fmaf(xf[k], kh[k], ax1);
        }
        dsum += xf[15];            // channel 15 = delta_x_shifted

        // ---- h-part: consume the hoisted reads ----
        {
            const float4 q[16] = {p0,p1,p2,p3,p4,p5,p6,p7,
                                  p8,p9,p10,p11,p12,p13,p14,p15};
#pragma unroll
            for (int i = 0; i < 8; ++i) {
                float4 p = q[i];
                az0 = fmaf(p.x, wz[4*i+0], az0);
                ar0 = fmaf(p.x, wr[4*i+0], ar0);
                ah0 = fmaf(p.x, wh[4*i+0], ah0);
                az0 = fmaf(p.y, wz[4*i+1], az0);
                ar0 = fmaf(p.y, wr[4*i+1], ar0);
                ah0 = fmaf(p.y, wh[4*i+1], ah0);
                az0 = fmaf(p.z, wz[4*i+2], az0);
                ar0 = fmaf(p.z, wr[4*i+2], ar0);
                ah0 = fmaf(p.z, wh[4*i+2], ah0);
                az0 = fmaf(p.w, wz[4*i+3], az0);
                ar0 = fmaf(p.w, wr[4*i+3], ar0);
                ah0 = fmaf(p.w, wh[4*i+3], ah0);
            }
#pragma unroll
            for (int i = 8; i < 16; ++i) {
                float4 p = q[i];
                az1 = fmaf(p.x, wz[4*i+0], az1);
                ar1 = fmaf(p.x, wr[4*i+0], ar1);
                ah1 = fmaf(p.x, wh[4*i+0], ah1);
                az1 = fmaf(p.y, wz[4*i+1], az1);
                ar1 = fmaf(p.y, wr[4*i+1], ar1);
                ah1 = fmaf(p.y, wh[4*i+1], ah1);
                az1 = fmaf(p.z, wz[4*i+2], az1);
                ar1 = fmaf(p.z, wr[4*i+2], ar1);
                ah1 = fmaf(p.z, wh[4*i+2], ah1);
                az1 = fmaf(p.w, wz[4*i+3], az1);
                ar1 = fmaf(p.w, wr[4*i+3], ar1);
                ah1 = fmaf(p.w, wh[4*i+3], ah1);
            }
        }

        const float az = az0 + az1;
        const float ar = ar0 + ar1;
        const float ax = ax0 + ax1;
        const float ah = ah0 + ah1;

        const float z   = __builtin_amdgcn_rcpf(1.0f + __expf(-az));
        const float r   = __builtin_amdgcn_rcpf(1.0f + __expf(-ar));
        const float pre = fmaf(r, ah, ax);
        const float e2  = __expf(2.0f * pre);
        const float th  = 1.0f - 2.0f * __builtin_amdgcn_rcpf(e2 + 1.0f);
        h = fmaf(z, h - th, th);   // z*h + (1-z)*tanh

        hs[j] = h;                 // single buffer: all reads above precede
        asm volatile("" ::: "memory");   // pin DS order (no s_barrier)

        craw = nraw;
    }

    // ---- epilogue: delta effect + dense head, all in-wave ----
    const float T0 = io::ld(Tp, 0);
    sred[j] = fmaf(T0 * (1.0f / 1024.0f), dsum, h);
    asm volatile("" ::: "memory");

    float acc = io::ld(b1v, j);
#pragma unroll
    for (int k = 0; k < 64; ++k)
        acc = fmaf(sred[k], io::ld(w1, k*64 + j), acc);
    acc = fmaxf(acc, 0.0f);                                  // ReLU
    const float inv = rsqrtf(io::ld(vav, j) + 0.001f);       // BN_EPS
    acc = fmaf((acc - io::ld(muv, j)) * inv, io::ld(gam, j), io::ld(bet, j));

    float v = acc * io::ld(w2, j);
#pragma unroll
    for (int off = 32; off > 0; off >>= 1)
        v += __shfl_down(v, off);
    if (j == 0) io::st(out, b, v + io::ld(bb2, 0));
}

extern "C" void kernel_launch(void* const* d_in, const int* in_sizes, int n_in,
                              void* d_out, int out_size, void* d_ws, size_t ws_size,
                              hipStream_t stream)
{
    const void* inp = d_in[0];   // (512,1024,16)
    const void* gk  = d_in[1];   // (15,192)
    const void* rk  = d_in[2];   // (64,192)
    const void* gb  = d_in[3];   // (2,192)
    const void* w1  = d_in[4];   // (64,64)
    const void* b1v = d_in[5];   // (64,)
    const void* gam = d_in[6];
    const void* bet = d_in[7];
    const void* muv = d_in[8];
    const void* vav = d_in[9];
    const void* w2  = d_in[10];  // (64,1)
    const void* bb2 = d_in[11];  // (1,)
    const void* Tp  = d_in[12];  // (1,)

    int* flag = (int*)d_ws;
    detect_dtype_kernel<<<dim3(1), dim3(1), 0, stream>>>(rk, flag);
    gru_full_kernel<true ><<<dim3(512), dim3(64), 0, stream>>>(
        inp, gk, rk, gb, w1, b1v, gam, bet, muv, vav, w2, bb2, Tp, flag, d_out);
    gru_full_kernel<false><<<dim3(512), dim3(64), 0, stream>>>(
        inp, gk, rk, gb, w1, b1v, gam, bet, muv, vav, w2, bb2, Tp, flag, d_out);
}

// Round 8
// 706.978 us; speedup vs baseline: 2.9708x; 1.4688x over previous
//
#include <hip/hip_runtime.h>
#include <hip/hip_bf16.h>

// NewellGRUModel: B=512, S=1024, F=16, H=64.  bf16 in/out (proven r2/r5/r6/r7).
//
// Diagnosis r2/r6/r7: VGPR_Count 136-144 with 237 "register" weights means the
// compiler REMATERIALIZED weight loads from global every step (L1 hits, ~200cyc,
// invisible in FETCH_SIZE) -> ~1700 stall cyc/step regardless of structure.
// Fix: split K across TWO waves per block (128 thr): lane j of wave `half`
// computes partial gates over k in [32*half, 32*half+32). Per-thread weights
// 237 -> ~120 floats -> genuinely VGPR-resident. Per-wave FMA issue halves,
// occupancy doubles (4 waves/CU).
//  - ONE s_barrier per step: partial exchange via LDS, double-buffered by
//    step parity. h-broadcast is per-WAVE private (hs[half], in-order DS,
//    compiler fence only -- proven r5/r6/r7).
//  - x staged per 16-step tile in LDS as fp32 (r2-proven, coalesced);
//    prefetch issued AFTER the tile barrier to amortize the vmcnt drain.
//  - Both waves redundantly compute the gate nonlinearity (same partials ->
//    same h_new), so each wave updates its own hs copy with no extra barrier.
// Constructs strictly from the proven set: unions/shifts, fmaf, __expf, rcpf,
// float2/float4 LDS, __syncthreads, asm fence, __shfl_down, detect scaffold.

template<bool BF16>
struct IO {
    static __device__ __forceinline__ float ld(const void* p, int i) {
        if constexpr (BF16) {
            unsigned short u = ((const unsigned short*)p)[i];
            union { unsigned int ui; float f; } c; c.ui = (unsigned int)u << 16;
            return c.f;
        } else {
            return ((const float*)p)[i];
        }
    }
    static __device__ __forceinline__ void st(void* p, int i, float v) {
        if constexpr (BF16) ((__hip_bfloat16*)p)[i] = __float2bfloat16(v);
        else ((float*)p)[i] = v;
    }
};

// Load 2 consecutive x elements (i even) as fp32 pair.
template<bool BF16>
__device__ __forceinline__ float2 ldx2(const void* p, int i) {
    if constexpr (BF16) {
        unsigned int u = *(const unsigned int*)((const unsigned short*)p + i);
        union { unsigned int ui; float f; } a, b;
        a.ui = u << 16; b.ui = u & 0xffff0000u;   // elem i = low 16 (LE)
        return make_float2(a.f, b.f);
    } else {
        return *(const float2*)((const float*)p + i);
    }
}

// mode: 0 = buffers are bf16, 1 = buffers are fp32.
__global__ void detect_dtype_kernel(const void* rkbuf, int* flag) {
    const float* f = (const float*)rkbuf;
    int ok = 0;
    for (int i = 0; i < 64; ++i) {
        float a = fabsf(f[i]);
        ok += (a > 1e-5f && a < 2.0f) ? 1 : 0;
    }
    *flag = (ok >= 48) ? 1 : 0;
}

template<bool BF16>
__global__ __launch_bounds__(128, 1)
void gru_full_kernel(const void* __restrict__ inp, const void* __restrict__ gk,
                     const void* __restrict__ rk,  const void* __restrict__ gb,
                     const void* __restrict__ w1,  const void* __restrict__ b1v,
                     const void* __restrict__ gam, const void* __restrict__ bet,
                     const void* __restrict__ muv, const void* __restrict__ vav,
                     const void* __restrict__ w2,  const void* __restrict__ bb2,
                     const void* __restrict__ Tp,  const int* __restrict__ mode,
                     void* __restrict__ out)
{
    const int want = BF16 ? 0 : 1;
    if (*mode != want) return;   // uniform branch, whole block exits

    const int b    = blockIdx.x;
    const int tid  = threadIdx.x;     // 0..127
    const int j    = tid & 63;        // output / gate-column index
    const int half = tid >> 6;        // K-half this wave owns
    const int k0   = half * 32;

    __shared__ __align__(16) float xs[2][16][16];      // x tile (fp32)
    __shared__ __align__(16) float hs[2][64];          // per-WAVE h copy
    __shared__ __align__(16) float pbuf[2][4][64][2];  // [par][gate][j][half]
    __shared__ __align__(16) float sred[64];           // epilogue exchange

    using io = IO<BF16>;

    // ---- recurrent weights: 32 rows for this wave's K-half ----
    float wz[32], wr[32], wh[32];
#pragma unroll
    for (int i = 0; i < 32; ++i) {
        const int row = k0 + i;
        wz[i] = io::ld(rk, row*192 + j);
        wr[i] = io::ld(rk, row*192 + 64 + j);
        wh[i] = io::ld(rk, row*192 + 128 + j);
    }
    // ---- x-proj weights: half 0 -> ch 0..7, half 1 -> ch 8..14 (+0 pad) ----
    float kz[8], kr[8], kh[8];
#pragma unroll
    for (int c = 0; c < 8; ++c) {
        const int ch = 8*half + c;
        const bool v = (ch < 15);
        kz[c] = v ? io::ld(gk, ch*192 + j)       : 0.0f;
        kr[c] = v ? io::ld(gk, ch*192 + 64 + j)  : 0.0f;
        kh[c] = v ? io::ld(gk, ch*192 + 128 + j) : 0.0f;
    }
    // biases live only in half 0's partials
    const float pz_i = half ? 0.0f : (io::ld(gb, j)      + io::ld(gb, 192 + j));
    const float pr_i = half ? 0.0f : (io::ld(gb, 64 + j) + io::ld(gb, 192 + 64 + j));
    const float ph_i = half ? 0.0f : io::ld(gb, 192 + 128 + j);   // b_r[h]
    const float px_i = half ? 0.0f : io::ld(gb, 128 + j);         // b_i[h]
    const float hsel = half ? 1.0f : 0.0f;   // dsum selector (ch15 in half 1)

    hs[half][j] = 0.0f;                // h0 = 0 (own-wave copy)
    asm volatile("" ::: "memory");

    const int xbase = b * 16384;       // elements
    float2 xreg = ldx2<BF16>(inp, xbase + 2*tid);   // tile 0 (2 elems/thread)

    float h = 0.0f, dsum = 0.0f;

#pragma unroll 1
    for (int t = 0; t < 64; ++t) {
        // stage tile t (128 threads x 2 elems = 256)
        {
            const int e = 2*tid;
            *(float2*)&xs[t & 1][e >> 4][e & 15] = xreg;
        }
        __syncthreads();   // tile barrier: staging visible to both waves
        if (t < 63) xreg = ldx2<BF16>(inp, xbase + (t + 1) * 256 + 2*tid);

#pragma unroll 1
        for (int s2 = 0; s2 < 16; ++s2) {
            const int s   = t * 16 + s2;
            const int par = s & 1;

            // x row, this wave's 8 channels (broadcast reads)
            const float4* xr = (const float4*)&xs[t & 1][s2][8*half];
            float4 xa = xr[0], xc = xr[1];

            // h, this wave's K-half: 8 ds_read_b128 from OWN copy
            const float4* hp = (const float4*)&hs[half][k0];
            float4 p0 = hp[0], p1 = hp[1], p2 = hp[2], p3 = hp[3];
            float4 p4 = hp[4], p5 = hp[5], p6 = hp[6], p7 = hp[7];
            asm volatile("" ::: "memory");

            float az = pz_i, ar = pr_i, ah = ph_i, ax = px_i;
            // x part (8 ch; half 1's ch15 weight is 0-padded)
            az = fmaf(xa.x, kz[0], az); ar = fmaf(xa.x, kr[0], ar); ax = fmaf(xa.x, kh[0], ax);
            az = fmaf(xa.y, kz[1], az); ar = fmaf(xa.y, kr[1], ar); ax = fmaf(xa.y, kh[1], ax);
            az = fmaf(xa.z, kz[2], az); ar = fmaf(xa.z, kr[2], ar); ax = fmaf(xa.z, kh[2], ax);
            az = fmaf(xa.w, kz[3], az); ar = fmaf(xa.w, kr[3], ar); ax = fmaf(xa.w, kh[3], ax);
            az = fmaf(xc.x, kz[4], az); ar = fmaf(xc.x, kr[4], ar); ax = fmaf(xc.x, kh[4], ax);
            az = fmaf(xc.y, kz[5], az); ar = fmaf(xc.y, kr[5], ar); ax = fmaf(xc.y, kh[5], ax);
            az = fmaf(xc.z, kz[6], az); ar = fmaf(xc.z, kr[6], ar); ax = fmaf(xc.z, kh[6], ax);
            az = fmaf(xc.w, kz[7], az); ar = fmaf(xc.w, kr[7], ar); ax = fmaf(xc.w, kh[7], ax);
            dsum = fmaf(hsel, xc.w, dsum);   // ch15 (half 1 only)

            // h part: 32 k-values from the hoisted reads
            {
                const float4 q[8] = {p0, p1, p2, p3, p4, p5, p6, p7};
#pragma unroll
                for (int i = 0; i < 8; ++i) {
                    float4 p = q[i];
                    az = fmaf(p.x, wz[4*i+0], az);
                    ar = fmaf(p.x, wr[4*i+0], ar);
                    ah = fmaf(p.x, wh[4*i+0], ah);
                    az = fmaf(p.y, wz[4*i+1], az);
                    ar = fmaf(p.y, wr[4*i+1], ar);
                    ah = fmaf(p.y, wh[4*i+1], ah);
                    az = fmaf(p.z, wz[4*i+2], az);
                    ar = fmaf(p.z, wr[4*i+2], ar);
                    ah = fmaf(p.z, wh[4*i+2], ah);
                    az = fmaf(p.w, wz[4*i+3], az);
                    ar = fmaf(p.w, wr[4*i+3], ar);
                    ah = fmaf(p.w, wh[4*i+3], ah);
                }
            }

            // exchange partials (double-buffered by step parity)
            pbuf[par][0][j][half] = az;
            pbuf[par][1][j][half] = ar;
            pbuf[par][2][j][half] = ah;
            pbuf[par][3][j][half] = ax;
            __syncthreads();   // the ONE barrier per step

            const float2 qz = *(const float2*)&pbuf[par][0][j][0];
            const float2 qr = *(const float2*)&pbuf[par][1][j][0];
            const float2 qh = *(const float2*)&pbuf[par][2][j][0];
            const float2 qx = *(const float2*)&pbuf[par][3][j][0];
            const float AZ = qz.x + qz.y;
            const float AR = qr.x + qr.y;
            const float AH = qh.x + qh.y;
            const float AX = qx.x + qx.y;

            const float z   = __builtin_amdgcn_rcpf(1.0f + __expf(-AZ));
            const float r   = __builtin_amdgcn_rcpf(1.0f + __expf(-AR));
            const float pre = fmaf(r, AH, AX);
            const float e2  = __expf(2.0f * pre);
            const float th  = 1.0f - 2.0f * __builtin_amdgcn_rcpf(e2 + 1.0f);
            h = fmaf(z, h - th, th);   // z*h + (1-z)*tanh  (both waves, same)

            hs[half][j] = h;           // own-wave copy; in-order DS
            asm volatile("" ::: "memory");
        }
    }

    __syncthreads();
    // ---- epilogue on wave 1 only (it owns dsum); wave 0 exits ----
    if (half == 1) {
        const float T0 = io::ld(Tp, 0);
        sred[j] = fmaf(T0 * (1.0f / 1024.0f), dsum, h);
        asm volatile("" ::: "memory");

        float acc = io::ld(b1v, j);
#pragma unroll
        for (int k = 0; k < 64; ++k)
            acc = fmaf(sred[k], io::ld(w1, k*64 + j), acc);
        acc = fmaxf(acc, 0.0f);                                  // ReLU
        const float inv = rsqrtf(io::ld(vav, j) + 0.001f);       // BN_EPS
        acc = fmaf((acc - io::ld(muv, j)) * inv, io::ld(gam, j), io::ld(bet, j));

        float v = acc * io::ld(w2, j);
#pragma unroll
        for (int off = 32; off > 0; off >>= 1)
            v += __shfl_down(v, off);
        if (j == 0) io::st(out, b, v + io::ld(bb2, 0));
    }
}

extern "C" void kernel_launch(void* const* d_in, const int* in_sizes, int n_in,
                              void* d_out, int out_size, void* d_ws, size_t ws_size,
                              hipStream_t stream)
{
    const void* inp = d_in[0];   // (512,1024,16)
    const void* gk  = d_in[1];   // (15,192)
    const void* rk  = d_in[2];   // (64,192)
    const void* gb  = d_in[3];   // (2,192)
    const void* w1  = d_in[4];   // (64,64)
    const void* b1v = d_in[5];   // (64,)
    const void* gam = d_in[6];
    const void* bet = d_in[7];
    const void* muv = d_in[8];
    const void* vav = d_in[9];
    const void* w2  = d_in[10];  // (64,1)
    const void* bb2 = d_in[11];  // (1,)
    const void* Tp  = d_in[12];  // (1,)

    int* flag = (int*)d_ws;
    detect_dtype_kernel<<<dim3(1), dim3(1), 0, stream>>>(rk, flag);
    gru_full_kernel<true ><<<dim3(512), dim3(128), 0, stream>>>(
        inp, gk, rk, gb, w1, b1v, gam, bet, muv, vav, w2, bb2, Tp, flag, d_out);
    gru_full_kernel<false><<<dim3(512), dim3(128), 0, stream>>>(
        inp, gk, rk, gb, w1, b1v, gam, bet, muv, vav, w2, bb2, Tp, flag, d_out);
}